// Round 2
// baseline (169.957 us; speedup 1.0000x reference)
//
#include <hip/hip_runtime.h>
#include <math.h>

#define BATCH 65536
#define LHIST 128
#define HFUT  32
#define CH    16          // history chunk length (steps staged per load burst)

__device__ __forceinline__ float softplusf(float x) {
    // log(1+e^x), numerically stable; matches jax.nn.softplus (uniform, runs once)
    return fmaxf(x, 0.0f) + log1pf(expf(-fabsf(x)));
}

// 65536 threads / (256 CU x 4 SIMD) = exactly 1 wave/SIMD regardless of VGPRs.
// Occupancy is structurally 1 wave/SIMD -> ALL latency hiding must come from
// in-wave ILP; the prefetch pipeline below is pinned with sched_barrier so the
// compiler cannot sink the loads to their uses (it did at VGPR=80, exposing
// ~900cy HBM latency per chunk).
__global__ __launch_bounds__(256, 1) void kalman_fwd(
    const float* __restrict__ v_hist,
    const float* __restrict__ dt_hist,
    const float* __restrict__ x_obs,
    const float* __restrict__ v_fut,
    const float* __restrict__ dt_fut,
    const float* __restrict__ theta,
    float* __restrict__ out)
{
    const int b = blockIdx.x * blockDim.x + threadIdx.x;

    // ---- uniform parameter transforms (once per thread, wave-uniform) ----
    const float alpha = 1.0f / (1.0f + expf(-theta[0]));
    const float c     = softplusf(theta[1]);
    const float kappa = softplusf(theta[2]);
    const float vc    = softplusf(theta[3]);       // VC_MIN = 0
    const float qx    = expf(theta[4]);
    const float qu    = expf(theta[5]);
    const float Rn    = expf(theta[6]);
    const float qs    = expf(theta[7]);
    const float p0xx  = expf(theta[8]);
    const float p0uu  = expf(theta[9]);
    const float a1    = softplusf(theta[10]);
    const float d1    = softplusf(theta[11]);
    const float d2    = softplusf(theta[12]);
    const float d3    = softplusf(theta[13]);
    const float b1    = theta[14];
    const float b2    = theta[15];
    const float beta  = theta[16];
    const float rho_m = tanhf(theta[17]);
    const float qm    = expf(theta[18]);
    const float p0mm  = expf(theta[19]);
    const float vc2   = vc * vc;
    const float qxs   = qs * qx;
    const float qus   = qs * qu;
    const float rm2   = rho_m * rho_m;             // uniform: hoisted out of predict
    // exp(-alpha*dt) = exp2(nal2e*dt): 1 mul + 1 v_exp_f32 (vs libm expf call)
    const float nal2e = -alpha * 1.44269504088896340736f;

    // ---- per-thread state: s = (x,u,m); P symmetric 3x3 (6 uniques) ----
    float sx = 0.0f, su = 0.0f, sm = 0.0f;
    float p00 = p0xx, p01 = 0.0f, p02 = 0.0f, p11 = p0uu, p12 = 0.0f, p22 = p0mm;

    auto predict = [&](float v, float dv, float dt_raw) {
        float dt  = fmaxf(dt_raw, 1e-6f);
        float rho = __builtin_amdgcn_exp2f(nal2e * dt);
        float forcing = fmaxf(v * v - vc2, 0.0f);
        float cl = -a1 * su + b1 * v + b2 * dv
                 - d1 * su * su - d2 * su * fabsf(v) - d3 * su * fabsf(su);
        float kdt = kappa * dt;
        float x_p = sx + su * dt;
        float u_p = rho * su - kdt * sx + c * forcing * dt + cl * dt + beta * sm;
        float m_p = rho_m * sm;
        // F = [[1,dt,0],[-kdt,rho,beta],[0,0,rho_m]];  P_p = F P F^T + diag(q)
        float f0 = p00 + dt * p01;
        float f1 = p01 + dt * p11;
        float f2 = p02 + dt * p12;
        float g0 = -kdt * p00 + rho * p01 + beta * p02;
        float g1 = -kdt * p01 + rho * p11 + beta * p12;
        float g2 = -kdt * p02 + rho * p12 + beta * p22;
        float n00 = f0 + dt * f1 + qxs * dt;
        float n01 = -kdt * f0 + rho * f1 + beta * f2;
        float n02 = rho_m * f2;
        float n11 = -kdt * g0 + rho * g1 + beta * g2 + qus * dt;
        float n12 = rho_m * g2;
        float n22 = rm2 * p22 + qm;
        sx = x_p; su = u_p; sm = m_p;
        p00 = n00; p01 = n01; p02 = n02; p11 = n11; p12 = n12; p22 = n22;
    };

    auto update = [&](float y) {
        float innov = y - sx;
        float S    = p00 + Rn;
        float Sinv = __builtin_amdgcn_rcpf(S);
        float K0 = p00 * Sinv, K1 = p01 * Sinv, K2 = p02 * Sinv;
        sx += K0 * innov; su += K1 * innov; sm += K2 * innov;
        float a = 1.0f - K0;
        float n00 = a * a * p00 + Rn * K0 * K0;
        float n01 = a * (p01 - K1 * p00) + Rn * K0 * K1;
        float n02 = a * (p02 - K2 * p00) + Rn * K0 * K2;
        float n11 = S * K1 * K1 - 2.0f * K1 * p01 + p11;
        float n12 = S * K1 * K2 - K2 * p01 - K1 * p02 + p12;
        float n22 = S * K2 * K2 - 2.0f * K2 * p02 + p22;
        p00 = n00; p01 = n01; p02 = n02; p11 = n11; p12 = n12; p22 = n22;
    };

    const float4* v4  = (const float4*)(v_hist  + (size_t)b * LHIST);
    const float4* d4  = (const float4*)(dt_hist + (size_t)b * LHIST);
    const float4* y4  = (const float4*)(x_obs   + (size_t)b * LHIST);

    // ---- history: 8 chunks of 16 steps; double-buffered register staging ----
    // step t: v[t], dv = v[t]-v[t-1] (0 at t=0), dt = dt_hist[t+1], y = x_obs[t+1]
    float cv[CH], cd[CH], cy[CH];       // current chunk
    float nv[CH], nd[CH], ny[CH];       // prefetched next chunk

    auto load_chunk = [&](float (&vv)[CH], float (&dd)[CH], float (&yy)[CH], int k) {
        float4* V = (float4*)vv; float4* D = (float4*)dd; float4* Y = (float4*)yy;
        #pragma unroll
        for (int i = 0; i < CH / 4; ++i) {
            V[i] = v4[(CH / 4) * k + i];
            D[i] = d4[(CH / 4) * k + i];
            Y[i] = y4[(CH / 4) * k + i];
        }
    };

    // future inputs live in registers; loaded under the LAST history chunk so
    // the history->future transition has no exposed latency
    float vf[HFUT], df[HFUT];

    load_chunk(cv, cd, cy, 0);
    load_chunk(nv, nd, ny, 1);
    // pin: the two chunk loads must issue before any chunk-0 compute
    __builtin_amdgcn_sched_barrier(0);

    // chunk 0: steps t = 0..14
    sx = cy[0];                                    // s0.x = x_obs[b][0]
    predict(cv[0], 0.0f, cd[1]); update(cy[1]);    // t = 0
    #pragma unroll
    for (int i = 1; i < CH - 1; ++i) {             // t = 1..14
        predict(cv[i], cv[i] - cv[i - 1], cd[i + 1]); update(cy[i + 1]);
    }
    float v_bridge  = cv[CH - 1];
    float dv_bridge = cv[CH - 1] - cv[CH - 2];

    // chunks 1..6: each covers t = 16k-1 .. 16k+14, prefetching chunk k+1.
    // The sched_barrier after the prefetch issue forbids the compiler from
    // sinking those loads into the next iteration (which kills the pipeline
    // to save registers -- we have a 512-VGPR budget at 1 wave/SIMD, spend it).
    #pragma unroll 1
    for (int k = 1; k < LHIST / CH - 1; ++k) {
        #pragma unroll
        for (int i = 0; i < CH; ++i) { cv[i] = nv[i]; cd[i] = nd[i]; cy[i] = ny[i]; }
        load_chunk(nv, nd, ny, k + 1);             // prefetch ahead (~16 steps of cover)
        __builtin_amdgcn_sched_barrier(0);
        predict(v_bridge, dv_bridge, cd[0]); update(cy[0]);               // t=16k-1
        predict(cv[0], cv[0] - v_bridge, cd[1]); update(cy[1]);           // t=16k
        #pragma unroll
        for (int i = 1; i < CH - 1; ++i) {                                // t=16k+i
            predict(cv[i], cv[i] - cv[i - 1], cd[i + 1]); update(cy[i + 1]);
        }
        v_bridge  = cv[CH - 1];
        dv_bridge = cv[CH - 1] - cv[CH - 2];
    }

    // last history chunk, peeled: prefetch the FUTURE inputs under it
    {
        #pragma unroll
        for (int i = 0; i < CH; ++i) { cv[i] = nv[i]; cd[i] = nd[i]; cy[i] = ny[i]; }
        {
            const float4* vf4 = (const float4*)(v_fut  + (size_t)b * HFUT);
            const float4* df4 = (const float4*)(dt_fut + (size_t)b * HFUT);
            float4* VF = (float4*)vf; float4* DF = (float4*)df;
            #pragma unroll
            for (int i = 0; i < HFUT / 4; ++i) { VF[i] = vf4[i]; DF[i] = df4[i]; }
        }
        __builtin_amdgcn_sched_barrier(0);
        predict(v_bridge, dv_bridge, cd[0]); update(cy[0]);               // t=111
        predict(cv[0], cv[0] - v_bridge, cd[1]); update(cy[1]);           // t=112
        #pragma unroll
        for (int i = 1; i < CH - 1; ++i) {                                // t=112+i
            predict(cv[i], cv[i] - cv[i - 1], cd[i + 1]); update(cy[i + 1]);
        }
        v_bridge = cv[CH - 1];
    }
    // steps 0..126 done; v_bridge = v_hist[b][127]

    // ---- future rollout: 32 predicts, outputs staged in registers ----
    float oxp[HFUT], oxv[HFUT], oue[HFUT];
    float vp = v_bridge;
    #pragma unroll
    for (int j = 0; j < HFUT; ++j) {
        predict(vf[j], vf[j] - vp, df[j]);
        vp = vf[j];
        oxp[j] = sx; oxv[j] = p00; oue[j] = su;
    }

    // ---- back-to-back full-line burst stores (measured-ideal WRITE_SIZE) ----
    float4* xp = (float4*)(out + (size_t)b * HFUT);
    float4* xv = (float4*)(out + (size_t)BATCH * HFUT + (size_t)b * HFUT);
    float4* ue = (float4*)(out + 2 * (size_t)BATCH * HFUT + (size_t)b * HFUT);
    float4* OXP = (float4*)oxp; float4* OXV = (float4*)oxv; float4* OUE = (float4*)oue;
    #pragma unroll
    for (int i = 0; i < HFUT / 4; ++i) {
        xp[i] = OXP[i]; xv[i] = OXV[i]; ue[i] = OUE[i];
    }
}

extern "C" void kernel_launch(void* const* d_in, const int* in_sizes, int n_in,
                              void* d_out, int out_size, void* d_ws, size_t ws_size,
                              hipStream_t stream) {
    const float* v_hist  = (const float*)d_in[0];
    const float* dt_hist = (const float*)d_in[1];
    const float* x_obs   = (const float*)d_in[2];
    const float* v_fut   = (const float*)d_in[3];
    const float* dt_fut  = (const float*)d_in[4];
    const float* theta   = (const float*)d_in[5];
    float* out = (float*)d_out;

    dim3 grid(BATCH / 256), block(256);
    hipLaunchKernelGGL(kalman_fwd, grid, block, 0, stream,
                       v_hist, dt_hist, x_obs, v_fut, dt_fut, theta, out);
}